// Round 18
// baseline (343.383 us; speedup 1.0000x reference)
//
#include <hip/hip_runtime.h>
#include <hip/hip_bf16.h>

#define BB 2
#define SS 2048
#define DD 1024
#define HH 16
#define DKV 64

typedef __attribute__((ext_vector_type(8))) short short8;
typedef __attribute__((ext_vector_type(4))) short short4_t;
typedef __attribute__((ext_vector_type(4))) float f32x4;

#define MFMA16(a, b, c) __builtin_amdgcn_mfma_f32_16x16x32_bf16(a, b, c, 0, 0, 0)

__device__ __forceinline__ short f2bf(float f) {
    __hip_bfloat16 h = __float2bfloat16(f);
    union { __hip_bfloat16 h; short s; } u;
    u.h = h;
    return u.s;
}

// ---------------------------------------------------------------------------
// Weight transpose only: W[k][n] fp32 -> WT[n][k] bf16 (4 matrices).
// ---------------------------------------------------------------------------
__global__ __launch_bounds__(256) void wtrans_kernel(
    const float* __restrict__ w0, const float* __restrict__ w1,
    const float* __restrict__ w2, const float* __restrict__ w3,
    short* __restrict__ o0, short* __restrict__ o1,
    short* __restrict__ o2, short* __restrict__ o3)
{
    const int z = blockIdx.z;
    const int t = threadIdx.x;
    const float* W = (z == 0) ? w0 : (z == 1) ? w1 : (z == 2) ? w2 : w3;
    short* O = (z == 0) ? o0 : (z == 1) ? o1 : (z == 2) ? o2 : o3;
    __shared__ short T[64][72];
    const int k0 = blockIdx.x * 64, n0 = blockIdx.y * 64;
    const int row = t >> 2, c = (t & 3) * 16;
    const float* src = W + (size_t)(k0 + row) * DD + n0 + c;
    #pragma unroll
    for (int i = 0; i < 16; i += 4) {
        float4 f = *(const float4*)(src + i);
        T[c + i + 0][row] = f2bf(f.x);
        T[c + i + 1][row] = f2bf(f.y);
        T[c + i + 2][row] = f2bf(f.z);
        T[c + i + 3][row] = f2bf(f.w);
    }
    __syncthreads();
    const int nr = t >> 2, kc = (t & 3) * 16;
    *(short8*)(O + (size_t)(n0 + nr) * DD + k0 + kc)     = *(const short8*)&T[nr][kc];
    *(short8*)(O + (size_t)(n0 + nr) * DD + k0 + kc + 8) = *(const short8*)&T[nr][kc + 8];
}

// ---------------------------------------------------------------------------
// Fused projection GEMMs + mask pack. BK=64; A read as fp32 + converted
// during staging (eliminates the separate qkv bf16 copy stream).
// z=0: mask bit-pack; z=1,2 -> q,k [b][h][s][64]; z=3 -> vT[b][h][d][s].
// ---------------------------------------------------------------------------
__global__ __launch_bounds__(256) void proj3_kernel(
    const float* __restrict__ A0, const float* __restrict__ A1, const float* __restrict__ A2,
    const short* __restrict__ WT0, const short* __restrict__ WT1, const short* __restrict__ WT2,
    const float* __restrict__ bq, const float* __restrict__ bk, const float* __restrict__ bv,
    __hip_bfloat16* __restrict__ o0, __hip_bfloat16* __restrict__ o1, __hip_bfloat16* __restrict__ o2,
    const int* __restrict__ mask, unsigned long long* __restrict__ bits)
{
    const int t = threadIdx.x;
    const int lane = t & 63;
    const int wave = t >> 6;

    if (blockIdx.z == 0) {
        const int bid = blockIdx.y * 32 + blockIdx.x;
        const int base = bid * 512 + wave * 128;
        #pragma unroll 4
        for (int wi = base; wi < base + 128; ++wi) {
            const int mv = mask[(size_t)wi * 64 + lane];
            const unsigned long long bal = __ballot(mv != 0);
            if (lane == 0) bits[wi] = bal;
        }
        return;
    }

    const int z = blockIdx.z - 1;
    const float* A  = (z == 0) ? A0 : (z == 1) ? A1 : A2;
    const short* WT = (z == 0) ? WT0 : (z == 1) ? WT1 : WT2;
    const float* bias = (z == 0) ? bq : (z == 1) ? bk : bv;
    __hip_bfloat16* outh = (z == 0) ? o0 : (z == 1) ? o1 : o2;

    __shared__ __align__(16) short As[128][72];
    __shared__ __align__(16) short Bs[128][72];  // Bs[col][k]
    const int wm = wave >> 1, wn = wave & 1;
    const int m0 = blockIdx.x * 128, n0 = blockIdx.y * 128;
    const int lr = lane & 15;
    const int kb = (lane >> 4) * 8;
    const int row2 = t >> 1, kk2 = (t & 1) * 32;

    f32x4 acc[4][4] = {};

    for (int k0 = 0; k0 < DD; k0 += 64) {
        __syncthreads();
        {
            const float* srca = A + (size_t)(m0 + row2) * DD + k0 + kk2;
            #pragma unroll
            for (int i = 0; i < 4; ++i) {
                float4 fa = *(const float4*)(srca + i * 8);
                float4 fb = *(const float4*)(srca + i * 8 + 4);
                short8 vv = { f2bf(fa.x), f2bf(fa.y), f2bf(fa.z), f2bf(fa.w),
                              f2bf(fb.x), f2bf(fb.y), f2bf(fb.z), f2bf(fb.w) };
                *(short8*)&As[row2][kk2 + i * 8] = vv;
            }
        }
        {
            const short8* srcw = (const short8*)(WT + (size_t)(n0 + row2) * DD + k0 + kk2);
            *(short8*)&Bs[row2][kk2]      = srcw[0];
            *(short8*)&Bs[row2][kk2 + 8]  = srcw[1];
            *(short8*)&Bs[row2][kk2 + 16] = srcw[2];
            *(short8*)&Bs[row2][kk2 + 24] = srcw[3];
        }
        __syncthreads();
        #pragma unroll
        for (int half = 0; half < 2; ++half) {
            const int ko = half * 32 + kb;
            short8 af[4], bfr[4];
            #pragma unroll
            for (int i = 0; i < 4; i++) af[i]  = *(const short8*)&As[wm * 64 + i * 16 + lr][ko];
            #pragma unroll
            for (int j = 0; j < 4; j++) bfr[j] = *(const short8*)&Bs[wn * 64 + j * 16 + lr][ko];
            #pragma unroll
            for (int i = 0; i < 4; i++)
                #pragma unroll
                for (int j = 0; j < 4; j++)
                    acc[i][j] = MFMA16(af[i], bfr[j], acc[i][j]);
        }
    }

    if (z != 2) {
        #pragma unroll
        for (int j = 0; j < 4; j++) {
            const int col = n0 + wn * 64 + j * 16 + lr;
            const float bvv = bias[col];
            const int h = col >> 6, d = col & 63;
            #pragma unroll
            for (int i = 0; i < 4; i++) {
                #pragma unroll
                for (int r = 0; r < 4; r++) {
                    const int m = m0 + wm * 64 + i * 16 + (lane >> 4) * 4 + r;
                    const int b = m >> 11, s = m & (SS - 1);
                    outh[(((size_t)(b * HH + h)) * SS + s) * DKV + d] =
                        __float2bfloat16(acc[i][j][r] + bvv);
                }
            }
        }
    } else {
        short* vT = (short*)outh;
        #pragma unroll
        for (int j = 0; j < 4; j++) {
            const int col = n0 + wn * 64 + j * 16 + lr;
            const float bvv = bias[col];
            const int h = col >> 6, d = col & 63;
            #pragma unroll
            for (int i = 0; i < 4; i++) {
                const int m = m0 + wm * 64 + i * 16 + (lane >> 4) * 4;
                const int b = m >> 11, s = m & (SS - 1);
                short4_t pk;
                #pragma unroll
                for (int r = 0; r < 4; r++) pk[r] = f2bf(acc[i][j][r] + bvv);
                *(short4_t*)(vT + ((size_t)(b * HH + h) * DKV + d) * SS + s) = pk;
            }
        }
    }
}

// ---------------------------------------------------------------------------
// Attention kernel A (compute): QK + exp(unnorm) + row-sums + PV.
// (R10/R14 structure: single-depth register prefetch, dbuf LDS.)
// ---------------------------------------------------------------------------
__global__ __launch_bounds__(512) void attn_compute_kernel(
    const __hip_bfloat16* __restrict__ qh, const __hip_bfloat16* __restrict__ kh,
    const __hip_bfloat16* __restrict__ vT, const unsigned long long* __restrict__ bits,
    float* __restrict__ linvb, __hip_bfloat16* __restrict__ ctx)
{
    __shared__ __align__(16) short Ks[2][64][72];
    __shared__ __align__(16) short Vs[2][64][72];
    __shared__ __align__(16) short Ps[8][16][72];
    const int t = threadIdx.x, lane = t & 63, w = t >> 6;

    const int logical = (blockIdx.x & 7) * 64 + (blockIdx.x >> 3);
    const int qt = logical & 15;
    const int bh = logical >> 4;
    const int h = bh & (HH - 1);
    const int b = bh >> 4;
    const int q0w = qt * 128 + w * 16;
    const size_t headbase = (size_t)bh * SS * DKV;
    const int lr = lane & 15;
    const int kb = (lane >> 4) * 8;
    const int rbase = (lane >> 4) * 4;

    const short* kbase = (const short*)kh + headbase;
    const short* vbase = (const short*)vT + (size_t)bh * DKV * SS;
    const unsigned long long* bitrow = bits + ((size_t)b * SS + q0w) * (SS / 64);

    const int srow = t >> 3, sc8 = (t & 7) * 8;
    const short* kstg = kbase + (size_t)srow * DKV + sc8;
    const short* vstg = vbase + (size_t)srow * SS + sc8;

    const short* qrp = (const short*)qh + headbase + (size_t)(q0w + lr) * DKV;
    const short8 aq0 = *(const short8*)(qrp + kb);
    const short8 aq1 = *(const short8*)(qrp + 32 + kb);

    float lsum[4] = {0.f, 0.f, 0.f, 0.f};
    f32x4 cacc[4] = {};

    {
        short8 kreg = *(const short8*)(kstg);
        short8 vreg = *(const short8*)(vstg);
        *(short8*)&Ks[0][srow][sc8] = kreg;
        *(short8*)&Vs[0][srow][sc8] = vreg;
        __syncthreads();
        for (int kt = 0; kt < 32; ++kt) {
            const int cur = kt & 1;
            if (kt + 1 < 32) {
                kreg = *(const short8*)(kstg + (size_t)(kt + 1) * 64 * DKV);
                vreg = *(const short8*)(vstg + (size_t)(kt + 1) * 64);
            }
            f32x4 sc[4];
            __builtin_amdgcn_s_setprio(1);
            #pragma unroll
            for (int fc = 0; fc < 4; ++fc) {
                short8 bk0 = *(const short8*)&Ks[cur][fc * 16 + lr][kb];
                short8 bk1 = *(const short8*)&Ks[cur][fc * 16 + lr][32 + kb];
                f32x4 s = {0.f, 0.f, 0.f, 0.f};
                s = MFMA16(aq0, bk0, s);
                s = MFMA16(aq1, bk1, s);
                sc[fc] = s;
            }
            __builtin_amdgcn_s_setprio(0);
            unsigned long long mw[4];
            #pragma unroll
            for (int r = 0; r < 4; ++r)
                mw[r] = bitrow[(size_t)(rbase + r) * (SS / 64) + kt];
            #pragma unroll
            for (int fc = 0; fc < 4; ++fc)
                #pragma unroll
                for (int r = 0; r < 4; ++r) {
                    const bool masked = (mw[r] >> (fc * 16 + lr)) & 1ull;
                    const float p = masked ? 0.f : __expf(sc[fc][r] * 0.125f);
                    lsum[r] += p;
                    Ps[w][rbase + r][fc * 16 + lr] = f2bf(p);
                }
            short8 ap0 = *(const short8*)&Ps[w][lr][kb];
            short8 ap1 = *(const short8*)&Ps[w][lr][32 + kb];
            __builtin_amdgcn_s_setprio(1);
            #pragma unroll
            for (int fd = 0; fd < 4; ++fd) {
                short8 bv0 = *(const short8*)&Vs[cur][fd * 16 + lr][kb];
                short8 bv1 = *(const short8*)&Vs[cur][fd * 16 + lr][32 + kb];
                cacc[fd] = MFMA16(ap0, bv0, cacc[fd]);
                cacc[fd] = MFMA16(ap1, bv1, cacc[fd]);
            }
            __builtin_amdgcn_s_setprio(0);
            if (kt + 1 < 32) {
                *(short8*)&Ks[cur ^ 1][srow][sc8] = kreg;
                *(short8*)&Vs[cur ^ 1][srow][sc8] = vreg;
            }
            __syncthreads();
        }
    }
    #pragma unroll
    for (int r = 0; r < 4; r++) {
        float s = lsum[r];
        s += __shfl_xor(s, 1);
        s += __shfl_xor(s, 2);
        s += __shfl_xor(s, 4);
        s += __shfl_xor(s, 8);
        lsum[r] = s;
    }
    float linv[4];
    #pragma unroll
    for (int r = 0; r < 4; r++) linv[r] = 1.f / lsum[r];

    if (lr == 0) {
        #pragma unroll
        for (int r = 0; r < 4; r++)
            linvb[(size_t)bh * SS + q0w + rbase + r] = linv[r];
    }

    #pragma unroll
    for (int fd = 0; fd < 4; ++fd)
        #pragma unroll
        for (int r = 0; r < 4; r++) {
            const int qrow = q0w + rbase + r;
            ctx[((size_t)b * SS + qrow) * DD + h * DKV + fd * 16 + lr] =
                __float2bfloat16(cacc[fd][r] * linv[r]);
        }
}

// ---------------------------------------------------------------------------
// Merged kernel: z=0 -> output GEMM (BK=64); z=1..32 -> attn store slices
// (64q x 256k each; 36KB LDS).
// ---------------------------------------------------------------------------
__global__ __launch_bounds__(256) void outstore_kernel(
    const __hip_bfloat16* __restrict__ Actx, const short* __restrict__ WT,
    const float* __restrict__ bias, const float* __restrict__ resid,
    float* __restrict__ out,
    const __hip_bfloat16* __restrict__ qh, const __hip_bfloat16* __restrict__ kh,
    const unsigned long long* __restrict__ bits, const float* __restrict__ linvb,
    float* __restrict__ attn)
{
    __shared__ __align__(16) short LDSBUF[18432];   // 36KB, unioned
    const int t = threadIdx.x, lane = t & 63, w = t >> 6;
    const int lr = lane & 15;
    const int kb = (lane >> 4) * 8;

    if (blockIdx.z == 0) {
        // ---------------- output GEMM, BK=64 ----------------
        short (*As)[72] = (short(*)[72])LDSBUF;
        short (*Bs)[72] = (short(*)[72])(LDSBUF + 9216);
        const int wave = w;
        const int wm = wave >> 1, wn = wave & 1;
        const int m0 = blockIdx.x * 128, n0 = blockIdx.y * 128;
        const int row2 = t >> 1, kk2 = (t & 1) * 32;

        f32x4 acc[4][4] = {};

        for (int k0 = 0; k0 < DD; k0 += 64) {
            __syncthreads();
            {
                const short8* src = (const short8*)((const short*)Actx + (size_t)(m0 + row2) * DD + k0 + kk2);
                *(short8*)&As[row2][kk2]      = src[0];
                *(short8*)&As[row2][kk2 + 8]  = src[1];
                *(short8*)&As[row2][kk2 + 16] = src[2];
                *(short8*)&As[row2][kk2 + 24] = src[3];
            }
            {
                const short8* srcw = (const short8*)(WT + (size_t)(n0 + row2) * DD + k0 + kk2);
                *(short8*)&Bs[row2][kk2]      = srcw[0];
                *(short8*)&Bs[row2][kk2 + 8]  = srcw[1];
                *(short8*)&Bs[row2][kk2 + 16] = srcw[2];
                *(short8*)&Bs[row2][kk2 + 24] = srcw[3];
            }
            __syncthreads();
            #pragma unroll
            for (int half = 0; half < 2; ++half) {
                const int ko = half * 32 + kb;
                short8 af[4], bfr[4];
                #pragma unroll
                for (int i = 0; i < 4; i++) af[i]  = *(const short8*)&As[wm * 64 + i * 16 + lr][ko];
                #pragma unroll
                for (int j = 0; j < 4; j++) bfr[j] = *(const short8*)&Bs[wn * 64 + j * 16 + lr][ko];
                #pragma unroll
                for (int i = 0; i < 4; i++)
                    #pragma unroll
                    for (int j = 0; j < 4; j++)
                        acc[i][j] = MFMA16(af[i], bfr[j], acc[i][j]);
            }
        }

        #pragma unroll
        for (int j = 0; j < 4; j++) {
            const int col = n0 + wn * 64 + j * 16 + lr;
            const float bvv = bias[col];
            #pragma unroll
            for (int i = 0; i < 4; i++) {
                #pragma unroll
                for (int r = 0; r < 4; r++) {
                    const int m = m0 + wm * 64 + i * 16 + (lane >> 4) * 4 + r;
                    out[(size_t)m * DD + col] = acc[i][j][r] + bvv + resid[(size_t)m * DD + col];
                }
            }
        }
        return;
    }

    // ---------------- attn store slice: 64q x 256k ----------------
    short (*Ks)[72] = (short(*)[72])LDSBUF;         // 256 x 72
    const int sb = (blockIdx.z - 1) * 256 + blockIdx.y * 32 + blockIdx.x;  // 0..8191
    const int qt = sb & 31;
    const int kc = (sb >> 5) & 7;
    const int bh = sb >> 8;
    const int b = bh >> 4;
    const int q0w = qt * 64 + w * 16;
    const int k0c = kc * 256;
    const size_t headbase = (size_t)bh * SS * DKV;
    const int Q4 = lane >> 4;
    const int rbase = Q4 * 4;

    {
        const short* kbase = (const short*)kh + headbase + (size_t)k0c * DKV;
        const int c8 = (t & 7) * 8;
        #pragma unroll
        for (int sweep = 0; sweep < 8; ++sweep) {
            const int row = (t >> 3) + sweep * 32;
            *(short8*)&Ks[row][c8] = *(const short8*)(kbase + (size_t)row * DKV + c8);
        }
    }

    const short* qrp = (const short*)qh + headbase + (size_t)(q0w + lr) * DKV;
    const short8 aq0 = *(const short8*)(qrp + kb);
    const short8 aq1 = *(const short8*)(qrp + 32 + kb);

    float linv[4];
    #pragma unroll
    for (int r = 0; r < 4; ++r)
        linv[r] = linvb[(size_t)bh * SS + q0w + rbase + r];

    const unsigned long long* bitrow = bits + ((size_t)b * SS + q0w) * (SS / 64);
    float* arow = attn + ((size_t)bh * SS + q0w) * SS + k0c;

    __syncthreads();

    for (int g = 0; g < 4; ++g) {
        unsigned long long mw[4];
        #pragma unroll
        for (int r = 0; r < 4; ++r)
            mw[r] = bitrow[(size_t)(rbase + r) * (SS / 64) + kc * 4 + g];
        #pragma unroll
        for (int fc = 0; fc < 4; ++fc) {
            const int col = g * 64 + fc * 16;
            short8 bk0 = *(const short8*)&Ks[col + lr][kb];
            short8 bk1 = *(const short8*)&Ks[col + lr][32 + kb];
            f32x4 s = {0.f, 0.f, 0.f, 0.f};
            s = MFMA16(aq0, bk0, s);
            s = MFMA16(aq1, bk1, s);
            #pragma unroll
            for (int r = 0; r < 4; ++r) {
                const bool masked = (mw[r] >> (fc * 16 + lr)) & 1ull;
                const float p = masked ? 0.f : __expf(s[r] * 0.125f) * linv[r];
                arow[(size_t)(rbase + r) * SS + col + lr] = p;
            }
        }
    }
}

// ---------------------------------------------------------------------------
// LayerNorm in place on out[4096][1024]; 4 rows per block. Biased var.
// ---------------------------------------------------------------------------
__global__ __launch_bounds__(256) void ln_kernel(
    float* __restrict__ io, const float* __restrict__ g, const float* __restrict__ bta)
{
    const int t = threadIdx.x;
    __shared__ float as_[4], bs_[4];
    const int w = t >> 6, l = t & 63;
    const float4 gv = *(const float4*)(g + t * 4);
    const float4 bv = *(const float4*)(bta + t * 4);

    #pragma unroll 1
    for (int rr = 0; rr < 4; ++rr) {
        const int row = blockIdx.x * 4 + rr;
        float* p = io + (size_t)row * DD;
        float4 x = *(float4*)(p + t * 4);
        float s  = x.x + x.y + x.z + x.w;
        float s2 = x.x * x.x + x.y * x.y + x.z * x.z + x.w * x.w;
        #pragma unroll
        for (int off = 32; off; off >>= 1) {
            s  += __shfl_xor(s, off);
            s2 += __shfl_xor(s2, off);
        }
        if (!l) { as_[w] = s; bs_[w] = s2; }
        __syncthreads();
        s  = as_[0] + as_[1] + as_[2] + as_[3];
        s2 = bs_[0] + bs_[1] + bs_[2] + bs_[3];
        const float mu  = s * (1.f / DD);
        const float var = s2 * (1.f / DD) - mu * mu;
        const float rs  = rsqrtf(var + 1e-5f);
        float4 o;
        o.x = (x.x - mu) * rs * gv.x + bv.x;
        o.y = (x.y - mu) * rs * gv.y + bv.y;
        o.z = (x.z - mu) * rs * gv.z + bv.z;
        o.w = (x.w - mu) * rs * gv.w + bv.w;
        *(float4*)(p + t * 4) = o;
        __syncthreads();   // recycle as_/bs_ next row
    }
}

// ---------------------------------------------------------------------------
extern "C" void kernel_launch(void* const* d_in, const int* in_sizes, int n_in,
                              void* d_out, int out_size, void* d_ws, size_t ws_size,
                              hipStream_t stream)
{
    (void)in_sizes; (void)n_in; (void)out_size; (void)ws_size;
    const float* q     = (const float*)d_in[0];
    const float* k     = (const float*)d_in[1];
    const float* v     = (const float*)d_in[2];
    const int*   mask  = (const int*)d_in[3];
    const float* wq    = (const float*)d_in[4];
    const float* bq    = (const float*)d_in[5];
    const float* wk    = (const float*)d_in[6];
    const float* bk    = (const float*)d_in[7];
    const float* wv    = (const float*)d_in[8];
    const float* bv    = (const float*)d_in[9];
    const float* wo    = (const float*)d_in[10];
    const float* bo    = (const float*)d_in[11];
    const float* gamma = (const float*)d_in[12];
    const float* beta  = (const float*)d_in[13];

    float* out  = (float*)d_out;                    // [B,S,D]
    float* attn = out + (size_t)BB * SS * DD;       // [B,H,S,S]

    const size_t hsz = (size_t)BB * HH * SS * DKV;  // 4,194,304
    __hip_bfloat16* qhp = (__hip_bfloat16*)d_ws;
    __hip_bfloat16* khp = qhp + hsz;
    __hip_bfloat16* vTp = khp + hsz;                // vT[b][h][d][s]
    __hip_bfloat16* ctx = vTp + hsz;
    unsigned long long* bits = (unsigned long long*)(ctx + hsz);       // 1 MB
    float* linvb = (float*)(bits + (size_t)BB * SS * (SS / 64));       // 256 KB
    short* wtq = (short*)(linvb + (size_t)BB * HH * SS);               // 4 x 2 MB
    short* wtk = wtq + (size_t)DD * DD;
    short* wtv = wtk + (size_t)DD * DD;
    short* wto = wtv + (size_t)DD * DD;

    dim3 gw(16, 16, 4);   // weights only
    wtrans_kernel<<<gw, 256, 0, stream>>>(wq, wk, wv, wo, wtq, wtk, wtv, wto);

    dim3 gg(32, 8, 4);    // z=0: mask pack; z=1..3: q/k/v projections
    proj3_kernel<<<gg, 256, 0, stream>>>(q, k, v, wtq, wtk, wtv, bq, bk, bv,
                                         qhp, khp, vTp, mask, bits);
    attn_compute_kernel<<<BB * HH * 16, 512, 0, stream>>>(qhp, khp, vTp, bits, linvb, ctx);

    dim3 gm(32, 8, 33);   // z=0: outproj; z=1..32: attn store slices (8192)
    outstore_kernel<<<gm, 256, 0, stream>>>(ctx, wto, bo, q, out,
                                            qhp, khp, bits, linvb, attn);
    ln_kernel<<<BB * SS / 4, 256, 0, stream>>>(out, gamma, beta);
}

// Round 19
// 317.463 us; speedup vs baseline: 1.0816x; 1.0816x over previous
//
#include <hip/hip_runtime.h>
#include <hip/hip_bf16.h>

#define BB 2
#define SS 2048
#define DD 1024
#define HH 16
#define DKV 64

typedef __attribute__((ext_vector_type(8))) short short8;
typedef __attribute__((ext_vector_type(4))) short short4_t;
typedef __attribute__((ext_vector_type(4))) float f32x4;

#define MFMA16(a, b, c) __builtin_amdgcn_mfma_f32_16x16x32_bf16(a, b, c, 0, 0, 0)

__device__ __forceinline__ short f2bf(float f) {
    __hip_bfloat16 h = __float2bfloat16(f);
    union { __hip_bfloat16 h; short s; } u;
    u.h = h;
    return u.s;
}

// ---------------------------------------------------------------------------
// z=0..3: W[k][n] fp32 -> WT[n][k] bf16.  z=4..6: q/k/v fp32 -> bf16 copy.
// ---------------------------------------------------------------------------
__global__ __launch_bounds__(256) void wtrans_kernel(
    const float* __restrict__ w0, const float* __restrict__ w1,
    const float* __restrict__ w2, const float* __restrict__ w3,
    const float* __restrict__ qf, const float* __restrict__ kf, const float* __restrict__ vf,
    short* __restrict__ o0, short* __restrict__ o1,
    short* __restrict__ o2, short* __restrict__ o3,
    short* __restrict__ oq, short* __restrict__ ok, short* __restrict__ ov)
{
    const int z = blockIdx.z;
    const int t = threadIdx.x;
    if (z >= 4) {
        const float* src = (z == 4) ? qf : (z == 5) ? kf : vf;
        short* dst = (z == 4) ? oq : (z == 5) ? ok : ov;
        size_t idx = ((size_t)(blockIdx.y * 16 + blockIdx.x) * 256 + t) * 8;
        #pragma unroll
        for (int it = 0; it < 8; ++it, idx += 524288) {
            float4 a = *(const float4*)(src + idx);
            float4 b = *(const float4*)(src + idx + 4);
            short8 p = { f2bf(a.x), f2bf(a.y), f2bf(a.z), f2bf(a.w),
                         f2bf(b.x), f2bf(b.y), f2bf(b.z), f2bf(b.w) };
            *(short8*)(dst + idx) = p;
        }
        return;
    }
    const float* W = (z == 0) ? w0 : (z == 1) ? w1 : (z == 2) ? w2 : w3;
    short* O = (z == 0) ? o0 : (z == 1) ? o1 : (z == 2) ? o2 : o3;
    __shared__ short T[64][72];
    const int k0 = blockIdx.x * 64, n0 = blockIdx.y * 64;
    const int row = t >> 2, c = (t & 3) * 16;
    const float* src = W + (size_t)(k0 + row) * DD + n0 + c;
    #pragma unroll
    for (int i = 0; i < 16; i += 4) {
        float4 f = *(const float4*)(src + i);
        T[c + i + 0][row] = f2bf(f.x);
        T[c + i + 1][row] = f2bf(f.y);
        T[c + i + 2][row] = f2bf(f.z);
        T[c + i + 3][row] = f2bf(f.w);
    }
    __syncthreads();
    const int nr = t >> 2, kc = (t & 3) * 16;
    *(short8*)(O + (size_t)(n0 + nr) * DD + k0 + kc)     = *(const short8*)&T[nr][kc];
    *(short8*)(O + (size_t)(n0 + nr) * DD + k0 + kc + 8) = *(const short8*)&T[nr][kc + 8];
}

// ---------------------------------------------------------------------------
// Fused projection GEMMs + mask pack. BK=64 (16 iters, 32 MFMA/iter).
// z=0: mask bit-pack; z=1,2 -> q,k [b][h][s][64]; z=3 -> vT[b][h][d][s].
// ---------------------------------------------------------------------------
__global__ __launch_bounds__(256) void proj3_kernel(
    const short* __restrict__ A0, const short* __restrict__ A1, const short* __restrict__ A2,
    const short* __restrict__ WT0, const short* __restrict__ WT1, const short* __restrict__ WT2,
    const float* __restrict__ bq, const float* __restrict__ bk, const float* __restrict__ bv,
    __hip_bfloat16* __restrict__ o0, __hip_bfloat16* __restrict__ o1, __hip_bfloat16* __restrict__ o2,
    const int* __restrict__ mask, unsigned long long* __restrict__ bits)
{
    const int t = threadIdx.x;
    const int lane = t & 63;
    const int wave = t >> 6;

    if (blockIdx.z == 0) {
        const int bid = blockIdx.y * 32 + blockIdx.x;
        const int base = bid * 512 + wave * 128;
        #pragma unroll 4
        for (int wi = base; wi < base + 128; ++wi) {
            const int mv = mask[(size_t)wi * 64 + lane];
            const unsigned long long bal = __ballot(mv != 0);
            if (lane == 0) bits[wi] = bal;
        }
        return;
    }

    const int z = blockIdx.z - 1;
    const short* A  = (z == 0) ? A0 : (z == 1) ? A1 : A2;
    const short* WT = (z == 0) ? WT0 : (z == 1) ? WT1 : WT2;
    const float* bias = (z == 0) ? bq : (z == 1) ? bk : bv;
    __hip_bfloat16* outh = (z == 0) ? o0 : (z == 1) ? o1 : o2;

    __shared__ __align__(16) short As[128][72];
    __shared__ __align__(16) short Bs[128][72];  // Bs[col][k]
    const int wm = wave >> 1, wn = wave & 1;
    const int m0 = blockIdx.x * 128, n0 = blockIdx.y * 128;
    const int lr = lane & 15;
    const int kb = (lane >> 4) * 8;
    const int row2 = t >> 1, kk2 = (t & 1) * 32;

    f32x4 acc[4][4] = {};

    for (int k0 = 0; k0 < DD; k0 += 64) {
        __syncthreads();
        {
            const short8* srca = (const short8*)(A + (size_t)(m0 + row2) * DD + k0 + kk2);
            *(short8*)&As[row2][kk2]      = srca[0];
            *(short8*)&As[row2][kk2 + 8]  = srca[1];
            *(short8*)&As[row2][kk2 + 16] = srca[2];
            *(short8*)&As[row2][kk2 + 24] = srca[3];
        }
        {
            const short8* srcw = (const short8*)(WT + (size_t)(n0 + row2) * DD + k0 + kk2);
            *(short8*)&Bs[row2][kk2]      = srcw[0];
            *(short8*)&Bs[row2][kk2 + 8]  = srcw[1];
            *(short8*)&Bs[row2][kk2 + 16] = srcw[2];
            *(short8*)&Bs[row2][kk2 + 24] = srcw[3];
        }
        __syncthreads();
        #pragma unroll
        for (int half = 0; half < 2; ++half) {
            const int ko = half * 32 + kb;
            short8 af[4], bfr[4];
            #pragma unroll
            for (int i = 0; i < 4; i++) af[i]  = *(const short8*)&As[wm * 64 + i * 16 + lr][ko];
            #pragma unroll
            for (int j = 0; j < 4; j++) bfr[j] = *(const short8*)&Bs[wn * 64 + j * 16 + lr][ko];
            #pragma unroll
            for (int i = 0; i < 4; i++)
                #pragma unroll
                for (int j = 0; j < 4; j++)
                    acc[i][j] = MFMA16(af[i], bfr[j], acc[i][j]);
        }
    }

    if (z != 2) {
        #pragma unroll
        for (int j = 0; j < 4; j++) {
            const int col = n0 + wn * 64 + j * 16 + lr;
            const float bvv = bias[col];
            const int h = col >> 6, d = col & 63;
            #pragma unroll
            for (int i = 0; i < 4; i++) {
                #pragma unroll
                for (int r = 0; r < 4; r++) {
                    const int m = m0 + wm * 64 + i * 16 + (lane >> 4) * 4 + r;
                    const int b = m >> 11, s = m & (SS - 1);
                    outh[(((size_t)(b * HH + h)) * SS + s) * DKV + d] =
                        __float2bfloat16(acc[i][j][r] + bvv);
                }
            }
        }
    } else {
        short* vT = (short*)outh;
        #pragma unroll
        for (int j = 0; j < 4; j++) {
            const int col = n0 + wn * 64 + j * 16 + lr;
            const float bvv = bias[col];
            const int h = col >> 6, d = col & 63;
            #pragma unroll
            for (int i = 0; i < 4; i++) {
                const int m = m0 + wm * 64 + i * 16 + (lane >> 4) * 4;
                const int b = m >> 11, s = m & (SS - 1);
                short4_t pk;
                #pragma unroll
                for (int r = 0; r < 4; r++) pk[r] = f2bf(acc[i][j][r] + bvv);
                *(short4_t*)(vT + ((size_t)(b * HH + h) * DKV + d) * SS + s) = pk;
            }
        }
    }
}

// ---------------------------------------------------------------------------
// Attention kernel A (compute): QK + exp(unnorm) + row-sums + PV.
// (R10/R14 structure: single-depth register prefetch, dbuf LDS.)
// ---------------------------------------------------------------------------
__global__ __launch_bounds__(512) void attn_compute_kernel(
    const __hip_bfloat16* __restrict__ qh, const __hip_bfloat16* __restrict__ kh,
    const __hip_bfloat16* __restrict__ vT, const unsigned long long* __restrict__ bits,
    float* __restrict__ linvb, __hip_bfloat16* __restrict__ ctx)
{
    __shared__ __align__(16) short Ks[2][64][72];
    __shared__ __align__(16) short Vs[2][64][72];
    __shared__ __align__(16) short Ps[8][16][72];
    const int t = threadIdx.x, lane = t & 63, w = t >> 6;

    const int logical = (blockIdx.x & 7) * 64 + (blockIdx.x >> 3);
    const int qt = logical & 15;
    const int bh = logical >> 4;
    const int h = bh & (HH - 1);
    const int b = bh >> 4;
    const int q0w = qt * 128 + w * 16;
    const size_t headbase = (size_t)bh * SS * DKV;
    const int lr = lane & 15;
    const int kb = (lane >> 4) * 8;
    const int rbase = (lane >> 4) * 4;

    const short* kbase = (const short*)kh + headbase;
    const short* vbase = (const short*)vT + (size_t)bh * DKV * SS;
    const unsigned long long* bitrow = bits + ((size_t)b * SS + q0w) * (SS / 64);

    const int srow = t >> 3, sc8 = (t & 7) * 8;
    const short* kstg = kbase + (size_t)srow * DKV + sc8;
    const short* vstg = vbase + (size_t)srow * SS + sc8;

    const short* qrp = (const short*)qh + headbase + (size_t)(q0w + lr) * DKV;
    const short8 aq0 = *(const short8*)(qrp + kb);
    const short8 aq1 = *(const short8*)(qrp + 32 + kb);

    float lsum[4] = {0.f, 0.f, 0.f, 0.f};
    f32x4 cacc[4] = {};

    {
        short8 kreg = *(const short8*)(kstg);
        short8 vreg = *(const short8*)(vstg);
        *(short8*)&Ks[0][srow][sc8] = kreg;
        *(short8*)&Vs[0][srow][sc8] = vreg;
        __syncthreads();
        for (int kt = 0; kt < 32; ++kt) {
            const int cur = kt & 1;
            if (kt + 1 < 32) {
                kreg = *(const short8*)(kstg + (size_t)(kt + 1) * 64 * DKV);
                vreg = *(const short8*)(vstg + (size_t)(kt + 1) * 64);
            }
            f32x4 sc[4];
            __builtin_amdgcn_s_setprio(1);
            #pragma unroll
            for (int fc = 0; fc < 4; ++fc) {
                short8 bk0 = *(const short8*)&Ks[cur][fc * 16 + lr][kb];
                short8 bk1 = *(const short8*)&Ks[cur][fc * 16 + lr][32 + kb];
                f32x4 s = {0.f, 0.f, 0.f, 0.f};
                s = MFMA16(aq0, bk0, s);
                s = MFMA16(aq1, bk1, s);
                sc[fc] = s;
            }
            __builtin_amdgcn_s_setprio(0);
            unsigned long long mw[4];
            #pragma unroll
            for (int r = 0; r < 4; ++r)
                mw[r] = bitrow[(size_t)(rbase + r) * (SS / 64) + kt];
            #pragma unroll
            for (int fc = 0; fc < 4; ++fc)
                #pragma unroll
                for (int r = 0; r < 4; ++r) {
                    const bool masked = (mw[r] >> (fc * 16 + lr)) & 1ull;
                    const float p = masked ? 0.f : __expf(sc[fc][r] * 0.125f);
                    lsum[r] += p;
                    Ps[w][rbase + r][fc * 16 + lr] = f2bf(p);
                }
            short8 ap0 = *(const short8*)&Ps[w][lr][kb];
            short8 ap1 = *(const short8*)&Ps[w][lr][32 + kb];
            __builtin_amdgcn_s_setprio(1);
            #pragma unroll
            for (int fd = 0; fd < 4; ++fd) {
                short8 bv0 = *(const short8*)&Vs[cur][fd * 16 + lr][kb];
                short8 bv1 = *(const short8*)&Vs[cur][fd * 16 + lr][32 + kb];
                cacc[fd] = MFMA16(ap0, bv0, cacc[fd]);
                cacc[fd] = MFMA16(ap1, bv1, cacc[fd]);
            }
            __builtin_amdgcn_s_setprio(0);
            if (kt + 1 < 32) {
                *(short8*)&Ks[cur ^ 1][srow][sc8] = kreg;
                *(short8*)&Vs[cur ^ 1][srow][sc8] = vreg;
            }
            __syncthreads();
        }
    }
    #pragma unroll
    for (int r = 0; r < 4; r++) {
        float s = lsum[r];
        s += __shfl_xor(s, 1);
        s += __shfl_xor(s, 2);
        s += __shfl_xor(s, 4);
        s += __shfl_xor(s, 8);
        lsum[r] = s;
    }
    float linv[4];
    #pragma unroll
    for (int r = 0; r < 4; r++) linv[r] = 1.f / lsum[r];

    if (lr == 0) {
        #pragma unroll
        for (int r = 0; r < 4; r++)
            linvb[(size_t)bh * SS + q0w + rbase + r] = linv[r];
    }

    #pragma unroll
    for (int fd = 0; fd < 4; ++fd)
        #pragma unroll
        for (int r = 0; r < 4; r++) {
            const int qrow = q0w + rbase + r;
            ctx[((size_t)b * SS + qrow) * DD + h * DKV + fd * 16 + lr] =
                __float2bfloat16(cacc[fd][r] * linv[r]);
        }
}

// ---------------------------------------------------------------------------
// Merged kernel: z=0 -> output GEMM (BK=64); z=1..32 -> attn store slices
// (64q x 256k each; 36KB LDS).
// ---------------------------------------------------------------------------
__global__ __launch_bounds__(256) void outstore_kernel(
    const __hip_bfloat16* __restrict__ Actx, const short* __restrict__ WT,
    const float* __restrict__ bias, const float* __restrict__ resid,
    float* __restrict__ out,
    const __hip_bfloat16* __restrict__ qh, const __hip_bfloat16* __restrict__ kh,
    const unsigned long long* __restrict__ bits, const float* __restrict__ linvb,
    float* __restrict__ attn)
{
    __shared__ __align__(16) short LDSBUF[18432];   // 36KB, unioned
    const int t = threadIdx.x, lane = t & 63, w = t >> 6;
    const int lr = lane & 15;
    const int kb = (lane >> 4) * 8;

    if (blockIdx.z == 0) {
        // ---------------- output GEMM, BK=64 ----------------
        short (*As)[72] = (short(*)[72])LDSBUF;
        short (*Bs)[72] = (short(*)[72])(LDSBUF + 9216);
        const int wave = w;
        const int wm = wave >> 1, wn = wave & 1;
        const int m0 = blockIdx.x * 128, n0 = blockIdx.y * 128;
        const int row2 = t >> 1, kk2 = (t & 1) * 32;

        f32x4 acc[4][4] = {};

        for (int k0 = 0; k0 < DD; k0 += 64) {
            __syncthreads();
            {
                const short8* src = (const short8*)((const short*)Actx + (size_t)(m0 + row2) * DD + k0 + kk2);
                *(short8*)&As[row2][kk2]      = src[0];
                *(short8*)&As[row2][kk2 + 8]  = src[1];
                *(short8*)&As[row2][kk2 + 16] = src[2];
                *(short8*)&As[row2][kk2 + 24] = src[3];
            }
            {
                const short8* srcw = (const short8*)(WT + (size_t)(n0 + row2) * DD + k0 + kk2);
                *(short8*)&Bs[row2][kk2]      = srcw[0];
                *(short8*)&Bs[row2][kk2 + 8]  = srcw[1];
                *(short8*)&Bs[row2][kk2 + 16] = srcw[2];
                *(short8*)&Bs[row2][kk2 + 24] = srcw[3];
            }
            __syncthreads();
            #pragma unroll
            for (int half = 0; half < 2; ++half) {
                const int ko = half * 32 + kb;
                short8 af[4], bfr[4];
                #pragma unroll
                for (int i = 0; i < 4; i++) af[i]  = *(const short8*)&As[wm * 64 + i * 16 + lr][ko];
                #pragma unroll
                for (int j = 0; j < 4; j++) bfr[j] = *(const short8*)&Bs[wn * 64 + j * 16 + lr][ko];
                #pragma unroll
                for (int i = 0; i < 4; i++)
                    #pragma unroll
                    for (int j = 0; j < 4; j++)
                        acc[i][j] = MFMA16(af[i], bfr[j], acc[i][j]);
            }
        }

        #pragma unroll
        for (int j = 0; j < 4; j++) {
            const int col = n0 + wn * 64 + j * 16 + lr;
            const float bvv = bias[col];
            #pragma unroll
            for (int i = 0; i < 4; i++) {
                #pragma unroll
                for (int r = 0; r < 4; r++) {
                    const int m = m0 + wm * 64 + i * 16 + (lane >> 4) * 4 + r;
                    out[(size_t)m * DD + col] = acc[i][j][r] + bvv + resid[(size_t)m * DD + col];
                }
            }
        }
        return;
    }

    // ---------------- attn store slice: 64q x 256k ----------------
    short (*Ks)[72] = (short(*)[72])LDSBUF;         // 256 x 72
    const int sb = (blockIdx.z - 1) * 256 + blockIdx.y * 32 + blockIdx.x;  // 0..8191
    const int qt = sb & 31;
    const int kc = (sb >> 5) & 7;
    const int bh = sb >> 8;
    const int b = bh >> 4;
    const int q0w = qt * 64 + w * 16;
    const int k0c = kc * 256;
    const size_t headbase = (size_t)bh * SS * DKV;
    const int Q4 = lane >> 4;
    const int rbase = Q4 * 4;

    {
        const short* kbase = (const short*)kh + headbase + (size_t)k0c * DKV;
        const int c8 = (t & 7) * 8;
        #pragma unroll
        for (int sweep = 0; sweep < 8; ++sweep) {
            const int row = (t >> 3) + sweep * 32;
            *(short8*)&Ks[row][c8] = *(const short8*)(kbase + (size_t)row * DKV + c8);
        }
    }

    const short* qrp = (const short*)qh + headbase + (size_t)(q0w + lr) * DKV;
    const short8 aq0 = *(const short8*)(qrp + kb);
    const short8 aq1 = *(const short8*)(qrp + 32 + kb);

    float linv[4];
    #pragma unroll
    for (int r = 0; r < 4; ++r)
        linv[r] = linvb[(size_t)bh * SS + q0w + rbase + r];

    const unsigned long long* bitrow = bits + ((size_t)b * SS + q0w) * (SS / 64);
    float* arow = attn + ((size_t)bh * SS + q0w) * SS + k0c;

    __syncthreads();

    for (int g = 0; g < 4; ++g) {
        unsigned long long mw[4];
        #pragma unroll
        for (int r = 0; r < 4; ++r)
            mw[r] = bitrow[(size_t)(rbase + r) * (SS / 64) + kc * 4 + g];
        #pragma unroll
        for (int fc = 0; fc < 4; ++fc) {
            const int col = g * 64 + fc * 16;
            short8 bk0 = *(const short8*)&Ks[col + lr][kb];
            short8 bk1 = *(const short8*)&Ks[col + lr][32 + kb];
            f32x4 s = {0.f, 0.f, 0.f, 0.f};
            s = MFMA16(aq0, bk0, s);
            s = MFMA16(aq1, bk1, s);
            #pragma unroll
            for (int r = 0; r < 4; ++r) {
                const bool masked = (mw[r] >> (fc * 16 + lr)) & 1ull;
                const float p = masked ? 0.f : __expf(s[r] * 0.125f) * linv[r];
                arow[(size_t)(rbase + r) * SS + col + lr] = p;
            }
        }
    }
}

// ---------------------------------------------------------------------------
// LayerNorm in place on out[4096][1024]; 4 rows per block. Biased var.
// ---------------------------------------------------------------------------
__global__ __launch_bounds__(256) void ln_kernel(
    float* __restrict__ io, const float* __restrict__ g, const float* __restrict__ bta)
{
    const int t = threadIdx.x;
    __shared__ float as_[4], bs_[4];
    const int w = t >> 6, l = t & 63;
    const float4 gv = *(const float4*)(g + t * 4);
    const float4 bv = *(const float4*)(bta + t * 4);

    #pragma unroll 1
    for (int rr = 0; rr < 4; ++rr) {
        const int row = blockIdx.x * 4 + rr;
        float* p = io + (size_t)row * DD;
        float4 x = *(float4*)(p + t * 4);
        float s  = x.x + x.y + x.z + x.w;
        float s2 = x.x * x.x + x.y * x.y + x.z * x.z + x.w * x.w;
        #pragma unroll
        for (int off = 32; off; off >>= 1) {
            s  += __shfl_xor(s, off);
            s2 += __shfl_xor(s2, off);
        }
        if (!l) { as_[w] = s; bs_[w] = s2; }
        __syncthreads();
        s  = as_[0] + as_[1] + as_[2] + as_[3];
        s2 = bs_[0] + bs_[1] + bs_[2] + bs_[3];
        const float mu  = s * (1.f / DD);
        const float var = s2 * (1.f / DD) - mu * mu;
        const float rs  = rsqrtf(var + 1e-5f);
        float4 o;
        o.x = (x.x - mu) * rs * gv.x + bv.x;
        o.y = (x.y - mu) * rs * gv.y + bv.y;
        o.z = (x.z - mu) * rs * gv.z + bv.z;
        o.w = (x.w - mu) * rs * gv.w + bv.w;
        *(float4*)(p + t * 4) = o;
        __syncthreads();   // recycle as_/bs_ next row
    }
}

// ---------------------------------------------------------------------------
extern "C" void kernel_launch(void* const* d_in, const int* in_sizes, int n_in,
                              void* d_out, int out_size, void* d_ws, size_t ws_size,
                              hipStream_t stream)
{
    (void)in_sizes; (void)n_in; (void)out_size; (void)ws_size;
    const float* q     = (const float*)d_in[0];
    const float* k     = (const float*)d_in[1];
    const float* v     = (const float*)d_in[2];
    const int*   mask  = (const int*)d_in[3];
    const float* wq    = (const float*)d_in[4];
    const float* bq    = (const float*)d_in[5];
    const float* wk    = (const float*)d_in[6];
    const float* bk    = (const float*)d_in[7];
    const float* wv    = (const float*)d_in[8];
    const float* bv    = (const float*)d_in[9];
    const float* wo    = (const float*)d_in[10];
    const float* bo    = (const float*)d_in[11];
    const float* gamma = (const float*)d_in[12];
    const float* beta  = (const float*)d_in[13];

    float* out  = (float*)d_out;                    // [B,S,D]
    float* attn = out + (size_t)BB * SS * DD;       // [B,H,S,S]

    const size_t hsz = (size_t)BB * HH * SS * DKV;  // 4,194,304
    __hip_bfloat16* qhp = (__hip_bfloat16*)d_ws;
    __hip_bfloat16* khp = qhp + hsz;
    __hip_bfloat16* vTp = khp + hsz;                // vT[b][h][d][s]
    __hip_bfloat16* ctx = vTp + hsz;
    unsigned long long* bits = (unsigned long long*)(ctx + hsz);       // 1 MB
    float* linvb = (float*)(bits + (size_t)BB * SS * (SS / 64));       // 256 KB
    short* wtq = (short*)(linvb + (size_t)BB * HH * SS);               // 4 x 2 MB
    short* wtk = wtq + (size_t)DD * DD;
    short* wtv = wtk + (size_t)DD * DD;
    short* wto = wtv + (size_t)DD * DD;
    short* qb  = wto + (size_t)DD * DD;                                // 3 x 8 MB
    short* kb2 = qb  + (size_t)BB * SS * DD;
    short* vb2 = kb2 + (size_t)BB * SS * DD;

    dim3 gw(16, 16, 7);   // z=0..3 wT; z=4..6 q/k/v -> bf16
    wtrans_kernel<<<gw, 256, 0, stream>>>(wq, wk, wv, wo, q, k, v,
                                          wtq, wtk, wtv, wto, qb, kb2, vb2);

    dim3 gg(32, 8, 4);    // z=0: mask pack; z=1..3: q/k/v projections
    proj3_kernel<<<gg, 256, 0, stream>>>(qb, kb2, vb2, wtq, wtk, wtv, bq, bk, bv,
                                         qhp, khp, vTp, mask, bits);
    attn_compute_kernel<<<BB * HH * 16, 512, 0, stream>>>(qhp, khp, vTp, bits, linvb, ctx);

    dim3 gm(32, 8, 33);   // z=0: outproj; z=1..32: attn store slices (8192)
    outstore_kernel<<<gm, 256, 0, stream>>>(ctx, wto, bo, q, out,
                                            qhp, khp, bits, linvb, attn);
    ln_kernel<<<BB * SS / 4, 256, 0, stream>>>(out, gamma, beta);
}